// Round 17
// baseline (316.345 us; speedup 1.0000x reference)
//
#include <hip/hip_runtime.h>
#include <hip/hip_bf16.h>

#define L   2304
#define D   256
#define NHD 8
#define HD  32
#define FF  1024
#define HH  48
#define WWW 48
#define SPL 4     // stage-1 attention split-K factor
#define NPS 144   // gn-stats partials per group (72 blocks x 2 row-half waves)
#define S2LOG 0.25503486f   // log2(e)/sqrt(32): folded into Q bf16 copy

typedef unsigned short bfraw;
typedef __attribute__((ext_vector_type(8))) short s8v;   // 8 bf16 = 4 VGPRs
typedef __attribute__((ext_vector_type(4))) float f4v;   // MFMA C/D frag

__device__ __forceinline__ bfraw f2b(float x) {
    __hip_bfloat16 h = __float2bfloat16(x);
    return __builtin_bit_cast(bfraw, h);
}

// Diagnostic: fill output with a constant (decodable from reported absmax).
__global__ __launch_bounds__(256) void diag_kernel(float* __restrict__ out, float c, int n)
{
    int i = blockIdx.x * 256 + threadIdx.x;
    if (i < n) out[i] = c;
}

// ---------------------------------------------------------------------------
// LayerNorm over D=256. fp32 out and bf16 out both OPTIONAL (nullable).
// ---------------------------------------------------------------------------
__global__ __launch_bounds__(256) void ln_kernel(
    const float* __restrict__ inA, const float* __restrict__ inB,
    const float* __restrict__ g, const float* __restrict__ b,
    float* __restrict__ out, bfraw* __restrict__ outb)
{
    int row = blockIdx.x, t = threadIdx.x;
    size_t idx = (size_t)row * D + t;
    float v = inA[idx];
    if (inB) v += inB[idx];
    __shared__ float rs[256], rq[256];
    rs[t] = v; rq[t] = v * v;
    __syncthreads();
    for (int o = 128; o > 0; o >>= 1) {
        if (t < o) { rs[t] += rs[t + o]; rq[t] += rq[t + o]; }
        __syncthreads();
    }
    float mean = rs[0] * (1.f / D);
    float var  = rq[0] * (1.f / D) - mean * mean;
    float rstd = rsqrtf(var + 1e-5f);
    float r = (v - mean) * rstd * g[t] + b[t];
    if (out)  out[idx]  = r;
    if (outb) outb[idx] = f2b(r);
}

// ---------------------------------------------------------------------------
// Merged ln2+ln4(v_st) AND stage-2 bf16 prep (cvt of gK, cvtT of gV).
// Grid (L + (2L/32)*(NHD+8)): bx < L -> dual layernorm row; else cvt work.
// ---------------------------------------------------------------------------
__global__ __launch_bounds__(256) void ln2cvt(
    const float* __restrict__ t5, const float* __restrict__ lV,
    const float* __restrict__ g2, const float* __restrict__ b2,
    const float* __restrict__ g4, const float* __restrict__ b4,
    bfraw* __restrict__ out2b, float* __restrict__ outv,
    const float* __restrict__ gK, bfraw* __restrict__ kb1,
    const float* __restrict__ gV, bfraw* __restrict__ vtb1)
{
    __shared__ float rs[256], rq[256];
    __shared__ float Ls[32][33];
    int t = threadIdx.x;
    if (blockIdx.x < L) {
        int row = blockIdx.x;
        size_t idx = (size_t)row * D + t;
        float v = t5[idx];
        rs[t] = v; rq[t] = v * v;
        __syncthreads();
        for (int o = 128; o > 0; o >>= 1) {
            if (t < o) { rs[t] += rs[t + o]; rq[t] += rq[t + o]; }
            __syncthreads();
        }
        float mean = rs[0] * (1.f / D);
        float var  = rq[0] * (1.f / D) - mean * mean;
        float rstd = rsqrtf(var + 1e-5f);
        float r2 = (v - mean) * rstd * g2[t] + b2[t];
        out2b[idx] = f2b(r2);
        float u = r2 + lV[idx];
        __syncthreads();
        rs[t] = u; rq[t] = u * u;
        __syncthreads();
        for (int o = 128; o > 0; o >>= 1) {
            if (t < o) { rs[t] += rs[t + o]; rq[t] += rq[t + o]; }
            __syncthreads();
        }
        float mean2 = rs[0] * (1.f / D);
        float var2  = rq[0] * (1.f / D) - mean2 * mean2;
        float rstd2 = rsqrtf(var2 + 1e-5f);
        outv[idx] = (u - mean2) * rstd2 * g4[t] + b4[t];
    } else {
        int idx = blockIdx.x - L;
        int ix = idx % (2 * L / 32), iy = idx / (2 * L / 32);
        if (iy < NHD) {
            int h = iy, n0 = ix * 32;
            const int N = 2 * L;
            int nl = t >> 3, dq = t & 7;
            float4 v = *reinterpret_cast<const float4*>(gV + (size_t)(n0 + nl) * D + h * HD + dq * 4);
            Ls[nl][dq*4+0] = v.x; Ls[nl][dq*4+1] = v.y;
            Ls[nl][dq*4+2] = v.z; Ls[nl][dq*4+3] = v.w;
            __syncthreads();
            int dl = t >> 3, nq = t & 7;
            ushort4 o;
            o.x = f2b(Ls[nq*4+0][dl]); o.y = f2b(Ls[nq*4+1][dl]);
            o.z = f2b(Ls[nq*4+2][dl]); o.w = f2b(Ls[nq*4+3][dl]);
            *reinterpret_cast<ushort4*>(vtb1 + (size_t)(h * HD + dl) * N + n0 + nq * 4) = o;
        } else {
            size_t i = ((size_t)(ix * 8 + (iy - NHD)) * 256 + t) * 4;
            float4 v = *reinterpret_cast<const float4*>(gK + i);
            ushort4 o;
            o.x = f2b(v.x); o.y = f2b(v.y); o.z = f2b(v.z); o.w = f2b(v.w);
            *reinterpret_cast<ushort4*>(kb1 + i) = o;
        }
    }
}

// ---------------------------------------------------------------------------
// Merged ln(k_st) + cvtT(v_st). Grid (L + L/32*NHD = 2880).
// ---------------------------------------------------------------------------
__global__ __launch_bounds__(256) void ln_cvtT(
    const float* __restrict__ t1, const float* __restrict__ lK,
    const float* __restrict__ g4, const float* __restrict__ b4,
    bfraw* __restrict__ kb2,
    const float* __restrict__ vsrc, bfraw* __restrict__ vtb2)
{
    __shared__ float rs[256], rq[256];
    __shared__ float Ls[32][33];
    int t = threadIdx.x;
    if (blockIdx.x < L) {
        int row = blockIdx.x;
        size_t idx = (size_t)row * D + t;
        float v = t1[idx] + lK[idx];
        rs[t] = v; rq[t] = v * v;
        __syncthreads();
        for (int o = 128; o > 0; o >>= 1) {
            if (t < o) { rs[t] += rs[t + o]; rq[t] += rq[t + o]; }
            __syncthreads();
        }
        float mean = rs[0] * (1.f / D);
        float var  = rq[0] * (1.f / D) - mean * mean;
        float rstd = rsqrtf(var + 1e-5f);
        kb2[idx] = f2b((v - mean) * rstd * g4[t] + b4[t]);
    } else {
        int idx = blockIdx.x - L;
        int n0 = (idx >> 3) * 32, h = idx & 7;
        int nl = t >> 3, dq = t & 7;
        float4 v = *reinterpret_cast<const float4*>(vsrc + (size_t)(n0 + nl) * D + h * HD + dq * 4);
        Ls[nl][dq*4+0] = v.x; Ls[nl][dq*4+1] = v.y;
        Ls[nl][dq*4+2] = v.z; Ls[nl][dq*4+3] = v.w;
        __syncthreads();
        int dl = t >> 3, nq = t & 7;
        ushort4 o;
        o.x = f2b(Ls[nq*4+0][dl]); o.y = f2b(Ls[nq*4+1][dl]);
        o.z = f2b(Ls[nq*4+2][dl]); o.w = f2b(Ls[nq*4+3][dl]);
        *reinterpret_cast<ushort4*>(vtb2 + (size_t)(h * HD + dl) * L + n0 + nq * 4) = o;
    }
}

// ---------------------------------------------------------------------------
// MFMA bf16 GEMM, bf16 A input (verified R7/R13 core): C = A@W^T + bias (+res).
// If ps2 != null (W1 call): each wave's 64 outputs lie in EXACTLY ONE
// 32-col group; wave-reduce (sum,sumsq) via shfl and lane 0 plain-stores to
// its unique slot ps2[g][bx*2 + (w&1)] -- deterministic, no atomics, every
// slot written once per launch (graph-replay safe, no zero-init).
// ---------------------------------------------------------------------------
__global__ __launch_bounds__(256) void gemm_mfma(
    const bfraw* __restrict__ A, const float* __restrict__ W,
    const float* __restrict__ bias, const float* res, float* out,
    bfraw* __restrict__ outb, float oscale, float* __restrict__ ps2,
    int M, int N, int K)
{
    __shared__ __attribute__((aligned(16))) short Wl[64][32];
    int t = threadIdx.x;
    int w = t >> 6, l = t & 63;
    int lo = l & 15, quad = l >> 4;
    int m0 = blockIdx.x * 32, n0 = blockIdx.y * 64;
    int wr = (w & 1) * 16, wc = (w >> 1) * 32;
    f4v acc[2];
    acc[0] = (f4v){0.f, 0.f, 0.f, 0.f};
    acc[1] = (f4v){0.f, 0.f, 0.f, 0.f};

    int aswz = (quad ^ ((lo >> 2) & 3)) * 8;   // swizzled k-group for W reads
    int srow = t >> 3, spart = t & 7;          // W staging: 32 rows x 8 quads
    const bfraw* ap = A + (size_t)(m0 + wr + lo) * K + quad * 8;

    for (int k0 = 0; k0 < K; k0 += 32) {
        float4 w4[2];
        #pragma unroll
        for (int i = 0; i < 2; i++)
            w4[i] = *reinterpret_cast<const float4*>(W + (size_t)(n0 + i * 32 + srow) * K + k0 + spart * 4);
        s8v af = *reinterpret_cast<const s8v*>(ap + k0);
        __syncthreads();
        #pragma unroll
        for (int i = 0; i < 2; i++) {
            int row = i * 32 + srow;
            int col = ((spart >> 1) ^ ((row >> 2) & 3)) * 8 + (spart & 1) * 4;
            ushort4 wb;
            wb.x = f2b(w4[i].x); wb.y = f2b(w4[i].y); wb.z = f2b(w4[i].z); wb.w = f2b(w4[i].w);
            *reinterpret_cast<ushort4*>(&Wl[row][col]) = wb;
        }
        __syncthreads();
        #pragma unroll
        for (int j = 0; j < 2; j++) {
            int rw = wc + j * 16 + lo;
            s8v wf = *reinterpret_cast<const s8v*>(&Wl[rw][aswz]);
            acc[j] = __builtin_amdgcn_mfma_f32_16x16x32_bf16(af, wf, acc[j], 0, 0, 0);
        }
    }

    float sl = 0.f, sq = 0.f;
    #pragma unroll
    for (int j = 0; j < 2; j++) {
        #pragma unroll
        for (int r = 0; r < 4; r++) {
            int mrow = m0 + wr + quad * 4 + r;
            int ncol = n0 + wc + j * 16 + lo;
            float v = acc[j][r] + bias[ncol];
            size_t idx = (size_t)mrow * N + ncol;
            if (res) v += res[idx];
            if (out) out[idx] = v;
            if (outb) outb[idx] = f2b(v * oscale);
            sl += v; sq += v * v;
        }
    }
    if (ps2) {
        #pragma unroll
        for (int off = 1; off < 64; off <<= 1) {
            sl += __shfl_xor(sl, off);
            sq += __shfl_xor(sq, off);
        }
        if (l == 0) {
            int g = (n0 + wc) >> 5;
            int slot = blockIdx.x * 2 + (w & 1);
            ps2[(g * NPS + slot) * 2]     = sl;
            ps2[(g * NPS + slot) * 2 + 1] = sq;
        }
    }
}

// ---------------------------------------------------------------------------
// DUAL GEMM: out = res + A1@W1^T + b1 + A2@W2^T + b2 (M=L, N=K=D fixed).
// ---------------------------------------------------------------------------
__global__ __launch_bounds__(256) void gemm_dual(
    const bfraw* __restrict__ A1, const float* __restrict__ W1, const float* __restrict__ b1,
    const bfraw* __restrict__ A2, const float* __restrict__ W2, const float* __restrict__ b2,
    const float* __restrict__ res, float* __restrict__ out)
{
    __shared__ __attribute__((aligned(16))) short Wl[64][32];
    int t = threadIdx.x;
    int w = t >> 6, l = t & 63;
    int lo = l & 15, quad = l >> 4;
    int m0 = blockIdx.x * 32, n0 = blockIdx.y * 64;
    int wr = (w & 1) * 16, wc = (w >> 1) * 32;
    f4v acc[2];
    acc[0] = (f4v){0.f, 0.f, 0.f, 0.f};
    acc[1] = (f4v){0.f, 0.f, 0.f, 0.f};

    int aswz = (quad ^ ((lo >> 2) & 3)) * 8;
    int srow = t >> 3, spart = t & 7;

    #pragma unroll
    for (int half = 0; half < 2; half++) {
        const bfraw* ap = (half ? A2 : A1) + (size_t)(m0 + wr + lo) * D + quad * 8;
        const float* W  = half ? W2 : W1;
        for (int k0 = 0; k0 < D; k0 += 32) {
            float4 w4[2];
            #pragma unroll
            for (int i = 0; i < 2; i++)
                w4[i] = *reinterpret_cast<const float4*>(W + (size_t)(n0 + i * 32 + srow) * D + k0 + spart * 4);
            s8v af = *reinterpret_cast<const s8v*>(ap + k0);
            __syncthreads();
            #pragma unroll
            for (int i = 0; i < 2; i++) {
                int row = i * 32 + srow;
                int col = ((spart >> 1) ^ ((row >> 2) & 3)) * 8 + (spart & 1) * 4;
                ushort4 wb;
                wb.x = f2b(w4[i].x); wb.y = f2b(w4[i].y); wb.z = f2b(w4[i].z); wb.w = f2b(w4[i].w);
                *reinterpret_cast<ushort4*>(&Wl[row][col]) = wb;
            }
            __syncthreads();
            #pragma unroll
            for (int j = 0; j < 2; j++) {
                int rw = wc + j * 16 + lo;
                s8v wf = *reinterpret_cast<const s8v*>(&Wl[rw][aswz]);
                acc[j] = __builtin_amdgcn_mfma_f32_16x16x32_bf16(af, wf, acc[j], 0, 0, 0);
            }
        }
    }

    #pragma unroll
    for (int j = 0; j < 2; j++) {
        #pragma unroll
        for (int r = 0; r < 4; r++) {
            int mrow = m0 + wr + quad * 4 + r;
            int ncol = n0 + wc + j * 16 + lo;
            size_t idx = (size_t)mrow * D + ncol;
            out[idx] = acc[j][r] + b1[ncol] + b2[ncol] + res[idx];
        }
    }
}

// ---------------------------------------------------------------------------
// Fused QKV projection (stage 1). Grid (L/32, 12): sel = by>>2 picks Q/K/V,
// n0 = (by&3)*64. Q -> qb bf16 (S2LOG); K -> kb bf16; V -> vtb TRANSPOSED.
// ---------------------------------------------------------------------------
__global__ __launch_bounds__(256) void gemm_qkv(
    const bfraw* __restrict__ A,
    const float* __restrict__ Wq_, const float* __restrict__ bq_,
    const float* __restrict__ Wk_, const float* __restrict__ bk_,
    const float* __restrict__ Wv_, const float* __restrict__ bv_,
    bfraw* __restrict__ qb, bfraw* __restrict__ kb, bfraw* __restrict__ vtb)
{
    __shared__ __attribute__((aligned(16))) short Wl[64][32];
    int t = threadIdx.x;
    int w = t >> 6, l = t & 63;
    int lo = l & 15, quad = l >> 4;
    int sel = blockIdx.y >> 2;
    int m0 = blockIdx.x * 32, n0 = (blockIdx.y & 3) * 64;
    int wr = (w & 1) * 16, wc = (w >> 1) * 32;
    const float* W    = (sel == 0) ? Wq_ : (sel == 1) ? Wk_ : Wv_;
    const float* bias = (sel == 0) ? bq_ : (sel == 1) ? bk_ : bv_;
    f4v acc[2];
    acc[0] = (f4v){0.f, 0.f, 0.f, 0.f};
    acc[1] = (f4v){0.f, 0.f, 0.f, 0.f};

    int aswz = (quad ^ ((lo >> 2) & 3)) * 8;
    int srow = t >> 3, spart = t & 7;
    const bfraw* ap = A + (size_t)(m0 + wr + lo) * D + quad * 8;

    for (int k0 = 0; k0 < D; k0 += 32) {
        float4 w4[2];
        #pragma unroll
        for (int i = 0; i < 2; i++)
            w4[i] = *reinterpret_cast<const float4*>(W + (size_t)(n0 + i * 32 + srow) * D + k0 + spart * 4);
        s8v af = *reinterpret_cast<const s8v*>(ap + k0);
        __syncthreads();
        #pragma unroll
        for (int i = 0; i < 2; i++) {
            int row = i * 32 + srow;
            int col = ((spart >> 1) ^ ((row >> 2) & 3)) * 8 + (spart & 1) * 4;
            ushort4 wb;
            wb.x = f2b(w4[i].x); wb.y = f2b(w4[i].y); wb.z = f2b(w4[i].z); wb.w = f2b(w4[i].w);
            *reinterpret_cast<ushort4*>(&Wl[row][col]) = wb;
        }
        __syncthreads();
        #pragma unroll
        for (int j = 0; j < 2; j++) {
            int rw = wc + j * 16 + lo;
            s8v wf = *reinterpret_cast<const s8v*>(&Wl[rw][aswz]);
            acc[j] = __builtin_amdgcn_mfma_f32_16x16x32_bf16(af, wf, acc[j], 0, 0, 0);
        }
    }

    #pragma unroll
    for (int j = 0; j < 2; j++) {
        #pragma unroll
        for (int r = 0; r < 4; r++) {
            int mrow = m0 + wr + quad * 4 + r;
            int ncol = n0 + wc + j * 16 + lo;
            float v = acc[j][r] + bias[ncol];
            if (sel == 0)      qb[(size_t)mrow * D + ncol] = f2b(v * S2LOG);
            else if (sel == 1) kb[(size_t)mrow * D + ncol] = f2b(v);
            else               vtb[(size_t)ncol * L + mrow] = f2b(v);   // transposed
        }
    }
}

// ---------------------------------------------------------------------------
// Attention core, FIXED-SHIFT softmax, DOUBLE-BUFFERED K/V staging (R16-
// verified): one barrier per 64-key step. PV swapped (mfma(V,P));
// LDS-transpose epilogue. OP unnormalized; ML stores just l per query.
// ---------------------------------------------------------------------------
__device__ __forceinline__ void attn_core(
    const bfraw* __restrict__ Qb, const bfraw* __restrict__ Kb,
    const bfraw* __restrict__ Vt, float* __restrict__ OP,
    float* __restrict__ ML, int Lk, int chunk, int zz,
    short (*Ks)[64][32], short (*Vts)[32][72], short (*Ps)[72], float (*Tb)[33])
{
    int t = threadIdx.x;
    int w = t >> 6, l = t & 63;
    int h = blockIdx.y, q0 = blockIdx.x * 64 + w * 16;
    int lo = l & 15, quad = l >> 4;
    int kb = zz * chunk, ke = kb + chunk;

    s8v qf = *reinterpret_cast<const s8v*>(Qb + (size_t)(q0 + lo) * D + h * HD + quad * 8);
    int kswz = (quad ^ ((lo >> 2) & 3)) * 8;

    int skey = t >> 2, spart = t & 3;
    int kcol = (spart ^ ((skey >> 2) & 3)) * 8;
    int sd = t >> 3, svp = t & 7;
    const bfraw* kp = Kb + (size_t)skey * D + h * HD + spart * 8;
    const bfraw* vp = Vt + (size_t)(h * HD + sd) * Lk + svp * 8;

    // prologue: stage first tile into buf 0
    {
        s8v kv = *reinterpret_cast<const s8v*>(kp + (size_t)kb * D);
        s8v vv = *reinterpret_cast<const s8v*>(vp + kb);
        *reinterpret_cast<s8v*>(&Ks[0][skey][kcol]) = kv;
        *reinterpret_cast<s8v*>(&Vts[0][sd][svp * 8]) = vv;
    }
    __syncthreads();

    float l_r = 0.f;
    f4v o0 = {0.f, 0.f, 0.f, 0.f}, o1 = {0.f, 0.f, 0.f, 0.f};
    int cur = 0;

    for (int k0 = kb; k0 < ke; k0 += 64) {
        bool hasNext = (k0 + 64) < ke;
        s8v nkv, nvv;
        if (hasNext) {
            nkv = *reinterpret_cast<const s8v*>(kp + (size_t)(k0 + 64) * D);
            nvv = *reinterpret_cast<const s8v*>(vp + (k0 + 64));
        }

        f4v sc4[4];
        #pragma unroll
        for (int s = 0; s < 4; s++) {
            s8v kf = *reinterpret_cast<const s8v*>(&Ks[cur][lo + 16 * s][kswz]);
            sc4[s] = __builtin_amdgcn_mfma_f32_16x16x32_bf16(kf, qf, (f4v){0.f,0.f,0.f,0.f}, 0, 0, 0);
        }
        float ls = 0.f;
        #pragma unroll
        for (int s = 0; s < 4; s++) {
            float p0 = __builtin_amdgcn_exp2f(sc4[s][0]);
            float p1 = __builtin_amdgcn_exp2f(sc4[s][1]);
            float p2 = __builtin_amdgcn_exp2f(sc4[s][2]);
            float p3 = __builtin_amdgcn_exp2f(sc4[s][3]);
            ls += p0 + p1 + p2 + p3;
            ushort4 pk;
            pk.x = f2b(p0); pk.y = f2b(p1); pk.z = f2b(p2); pk.w = f2b(p3);
            *reinterpret_cast<ushort4*>(&Ps[lo][s * 16 + quad * 4]) = pk;
        }
        ls += __shfl_xor(ls, 16);
        ls += __shfl_xor(ls, 32);
        l_r += ls;
        #pragma unroll
        for (int kc = 0; kc < 2; kc++) {
            s8v pf = *reinterpret_cast<const s8v*>(&Ps[lo][kc * 32 + quad * 8]);
            s8v v0 = *reinterpret_cast<const s8v*>(&Vts[cur][lo][kc * 32 + quad * 8]);
            s8v v1 = *reinterpret_cast<const s8v*>(&Vts[cur][16 + lo][kc * 32 + quad * 8]);
            o0 = __builtin_amdgcn_mfma_f32_16x16x32_bf16(v0, pf, o0, 0, 0, 0);
            o1 = __builtin_amdgcn_mfma_f32_16x16x32_bf16(v1, pf, o1, 0, 0, 0);
        }

        if (hasNext) {
            *reinterpret_cast<s8v*>(&Ks[cur ^ 1][skey][kcol]) = nkv;
            *reinterpret_cast<s8v*>(&Vts[cur ^ 1][sd][svp * 8]) = nvv;
        }
        __syncthreads();   // buf^1 writes visible AND buf reads done
        cur ^= 1;
    }

    #pragma unroll
    for (int r = 0; r < 4; r++) {
        Tb[lo][quad * 4 + r]      = o0[r];
        Tb[lo][16 + quad * 4 + r] = o1[r];
    }
    float* Oz = OP + (size_t)zz * L * D;
    int ql = l >> 2, dq = (l & 3) * 8;
    float4 u0, u1;
    u0.x = Tb[ql][dq + 0]; u0.y = Tb[ql][dq + 1];
    u0.z = Tb[ql][dq + 2]; u0.w = Tb[ql][dq + 3];
    u1.x = Tb[ql][dq + 4]; u1.y = Tb[ql][dq + 5];
    u1.z = Tb[ql][dq + 6]; u1.w = Tb[ql][dq + 7];
    *reinterpret_cast<float4*>(Oz + (size_t)(q0 + ql) * D + h * HD + dq)     = u0;
    *reinterpret_cast<float4*>(Oz + (size_t)(q0 + ql) * D + h * HD + dq + 4) = u1;
    if (l < 16)
        ML[((size_t)zz * NHD + h) * L + q0 + lo] = l_r;
}

// Stage-1 self attention, SPL=4. Grid (L/64, NHD, SPL).
__global__ __launch_bounds__(256) void attn_mfma_split(
    const bfraw* __restrict__ Qb, const bfraw* __restrict__ Kb,
    const bfraw* __restrict__ Vt, float* __restrict__ OP,
    float* __restrict__ ML, int Lk, int chunk)
{
    __shared__ __attribute__((aligned(16))) short Ks[2][64][32];
    __shared__ __attribute__((aligned(16))) short Vts[2][32][72];
    __shared__ __attribute__((aligned(16))) short Ps[4][16][72];
    __shared__ float Tb[4][16][33];
    int w = threadIdx.x >> 6;
    attn_core(Qb, Kb, Vt, OP, ML, Lk, chunk, blockIdx.z, Ks, Vts, Ps[w], Tb[w]);
}

// Stage-2 fused LT+ST attention, SPL=2 each. Grid (L/64, NHD, 4):
// z<2 -> LT chunk z; z>=2 -> ST chunk z-2.
__global__ __launch_bounds__(256) void attn_ltst(
    const bfraw* __restrict__ Qb,
    const bfraw* __restrict__ K_lt, const bfraw* __restrict__ V_lt,
    float* __restrict__ OP_lt, float* __restrict__ ML_lt,
    const bfraw* __restrict__ K_st, const bfraw* __restrict__ V_st,
    float* __restrict__ OP_st, float* __restrict__ ML_st)
{
    __shared__ __attribute__((aligned(16))) short Ks[2][64][32];
    __shared__ __attribute__((aligned(16))) short Vts[2][32][72];
    __shared__ __attribute__((aligned(16))) short Ps[4][16][72];
    __shared__ float Tb[4][16][33];
    int w = threadIdx.x >> 6;
    int z = blockIdx.z;
    if (z < 2)
        attn_core(Qb, K_lt, V_lt, OP_lt, ML_lt, 2 * L, L, z, Ks, Vts, Ps[w], Tb[w]);
    else
        attn_core(Qb, K_st, V_st, OP_st, ML_st, L, L / 2, z - 2, Ks, Vts, Ps[w], Tb[w]);
}

// Stage-1 combine, SPL=4: equal-weight (fixed-shift softmax) -> bf16.
__global__ __launch_bounds__(256) void attn_combine(
    const float* __restrict__ OP, const float* __restrict__ ML,
    bfraw* __restrict__ Ob)
{
    int q = blockIdx.x, t = threadIdx.x, h = t >> 5;
    float wl = 0.f, acc = 0.f;
    #pragma unroll
    for (int s = 0; s < SPL; s++) {
        wl  += ML[((size_t)s * NHD + h) * L + q];
        acc += OP[(size_t)s * L * D + (size_t)q * D + t];
    }
    Ob[(size_t)q * D + t] = f2b(acc / wl);
}

// Stage-2 combine for BOTH lt and st, SPL=2. Grid (L, 2).
__global__ __launch_bounds__(256) void combine2_both(
    const float* __restrict__ OP_lt, const float* __restrict__ ML_lt, bfraw* __restrict__ Ob_lt,
    const float* __restrict__ OP_st, const float* __restrict__ ML_st, bfraw* __restrict__ Ob_st)
{
    int q = blockIdx.x, t = threadIdx.x, h = t >> 5;
    const float* OP = blockIdx.y ? OP_st : OP_lt;
    const float* ML = blockIdx.y ? ML_st : ML_lt;
    bfraw* Ob = blockIdx.y ? Ob_st : Ob_lt;
    float wl = 0.f, acc = 0.f;
    #pragma unroll
    for (int s = 0; s < 2; s++) {
        wl  += ML[((size_t)s * NHD + h) * L + q];
        acc += OP[(size_t)s * L * D + (size_t)q * D + t];
    }
    Ob[(size_t)q * D + t] = f2b(acc / wl);
}

// ---------------------------------------------------------------------------
// Fused GN + exact-GELU + depthwise 5x5 conv. Stats arrive as NPS=144
// per-group partials written by the W1 GEMM's wave epilogue; each thread
// folds its group's partials (72 float4 L2-broadcast loads).
// Grid (6,6,16); 12x12 halo in LDS; output bf16 (feeds W2 GEMM).
// ---------------------------------------------------------------------------
__global__ __launch_bounds__(256) void gn_gelu_dwconv(
    const float* __restrict__ X, const float* __restrict__ ps,
    const float* __restrict__ gg, const float* __restrict__ gb,
    const float* __restrict__ Kw, bfraw* __restrict__ Y)
{
    __shared__ float tile[144][64];
    int h0 = blockIdx.x * 8, w0 = blockIdx.y * 8, c0 = blockIdx.z * 64;
    int t = threadIdx.x;
    int c = t & 63;
    int cg = (c0 + c) >> 5;
    float s = 0.f, sq = 0.f;
    const float4* p4 = reinterpret_cast<const float4*>(ps + (size_t)cg * NPS * 2);
    #pragma unroll 8
    for (int i = 0; i < NPS / 2; i++) {
        float4 v4 = p4[i];
        s  += v4.x + v4.z;
        sq += v4.y + v4.w;
    }
    float n = (float)(L * 32);
    float mu = s / n;
    float rs = rsqrtf(sq / n - mu * mu + 1e-5f);
    float ga = gg[c0 + c], be = gb[c0 + c];

    for (int i = t; i < 144 * 64; i += 256) {
        int sp = i >> 6;
        int hy = h0 + (sp / 12) - 2, wx = w0 + (sp % 12) - 2;
        float v = 0.f;
        if (hy >= 0 && hy < HH && wx >= 0 && wx < WWW) {
            float x = X[(size_t)(hy * WWW + wx) * FF + c0 + c];
            x = (x - mu) * rs * ga + be;
            v = 0.5f * x * (1.f + erff(x * 0.70710678118654752f));
        }
        tile[sp][c] = v;
    }
    float kw[25];
    #pragma unroll
    for (int i = 0; i < 25; i++) kw[i] = Kw[(size_t)(c0 + c) * 25 + i];
    __syncthreads();

    int sgrp = t >> 6;
    for (int sIdx = 0; sIdx < 16; sIdx++) {
        int sp = sgrp * 16 + sIdx;
        int oh = sp >> 3, ow = sp & 7;
        float acc = 0.f;
        #pragma unroll
        for (int ky = 0; ky < 5; ky++)
            #pragma unroll
            for (int kx = 0; kx < 5; kx++)
                acc += tile[(oh + ky) * 12 + ow + kx][c] * kw[ky * 5 + kx];
        Y[(size_t)((h0 + oh) * WWW + w0 + ow) * FF + c0 + c] = f2b(acc);
    }
}

// ---------------------------------------------------------------------------
extern "C" void kernel_launch(void* const* d_in, const int* in_sizes, int n_in,
                              void* d_out, int out_size, void* d_ws, size_t ws_size,
                              hipStream_t stream)
{
    (void)in_sizes;
    float* out = (float*)d_out;   // reference output dtype is float32

    if (n_in != 34) {
        diag_kernel<<<(out_size + 255) / 256, 256, 0, stream>>>(out, 2000.f, out_size);
        return;
    }

    const float* tgt    = (const float*)d_in[0];
    const float* gK     = (const float*)d_in[1];
    const float* gV     = (const float*)d_in[2];
    const float* lK     = (const float*)d_in[3];
    const float* lV     = (const float*)d_in[4];
    const float* ln1_g  = (const float*)d_in[5];
    const float* ln1_b  = (const float*)d_in[6];
    const float* ln2_g  = (const float*)d_in[7];
    const float* ln2_b  = (const float*)d_in[8];
    const float* ln3_g  = (const float*)d_in[9];
    const float* ln3_b  = (const float*)d_in[10];
    const float* ln4_g  = (const float*)d_in[11];
    const float* ln4_b  = (const float*)d_in[12];
    const float* sa_Wq  = (const float*)d_in[13];
    const float* sa_bq  = (const float*)d_in[14];
    const float* sa_Wk  = (const float*)d_in[15];
    const float* sa_bk  = (const float*)d_in[16];
    const float* sa_Wv  = (const float*)d_in[17];
    const float* sa_bv  = (const float*)d_in[18];
    const float* sa_Wo  = (const float*)d_in[19];
    const float* sa_bo  = (const float*)d_in[20];
    const float* Wq     = (const float*)d_in[21];
    const float* bq     = (const float*)d_in[22];
    const float* lt_Wo  = (const float*)d_in[23];
    const float* lt_bo  = (const float*)d_in[24];
    const float* st_Wo  = (const float*)d_in[25];
    const float* st_bo  = (const float*)d_in[26];
    const float* W1w    = (const float*)d_in[27];
    const float* b1w    = (const float*)d_in[28];
    const float* gn_g   = (const float*)d_in[29];
    const float* gn_b   = (const float*)d_in[30];
    const float* dw_k   = (const float*)d_in[31];
    const float* W2w    = (const float*)d_in[32];
    const float* b2w    = (const float*)d_in[33];

    // Workspace layout (see R7/R10/R13). PS = [32][NPS][2] partials in
    // X2 slack (9216 floats, written deterministically by W1 GEMM waves).
    const size_t LD = (size_t)L * D;
    const size_t NEED = (6 * LD + (size_t)L * FF + 64) * 4;
    float* ws = (float*)d_ws;
    float* t0 = ws + 0 * LD;
    float* t1 = ws + 1 * LD;
    float* t2 = ws + 2 * LD;
    float* t3 = ws + 3 * LD;
    float* t4 = ws + 4 * LD;
    float* t5 = ws + 5 * LD;
    float* X1 = t0;                   // [L,FF], spans t0..t3 (dead in stage 3)
    float* X2 = ws + 6 * LD;          // [L,FF] region
    bfraw* qb   = (bfraw*)X2;
    bfraw* kb1  = qb + LD;            // gK bf16 (2L)
    bfraw* vtb1 = qb + 3 * LD;        // gV^T bf16 (2L)
    bfraw* kb2  = qb + 5 * LD;        // self/st K bf16 (L)
    bfraw* vtb2 = qb + 6 * LD;        // self/st V^T bf16 (L)
    float* OP   = ws;                 // stage-1 partials: [4][L][D] = t0..t3
    float* OPlt = t0;                 // stage-2 LT partials: [2][L][D]
    float* OPst = t2;                 // stage-2 ST partials: [2][L][D]
    float* ML   = X2 + (7 * LD) / 2;  // stage-1 ML [4][NHD][L] (X2 slack)
    float* MLlt = ML;                 // stage-2 LT ML [2][NHD][L]
    float* MLst = ML + 2 * (size_t)NHD * L;
    float* PS   = ML;                 // gn stats partials [32][NPS][2] (stage 3)
    bfraw* t0b  = (bfraw*)t0;
    bfraw* t3b  = (bfraw*)t3;
    bfraw* t4b  = (bfraw*)t4;
    bfraw* obLT = t4b;
    bfraw* obST = t4b + LD;
    bfraw* X2b  = (bfraw*)X2;         // conv out bf16 (attn bufs dead in stage 3)

    if (ws_size < NEED) {
        int wsMiB = (int)(ws_size >> 20); if (wsMiB > 63) wsMiB = 63;
        diag_kernel<<<(out_size + 255) / 256, 256, 0, stream>>>(out, 64.f + (float)wsMiB, out_size);
        return;
    }

    dim3 gDD(L / 32, D / 64);         // (72, 4)
    dim3 gDF(L / 32, FF / 64);        // (72, 16)
    dim3 gQKV(L / 32, 12);            // fused QKV
    dim3 gATS(L / 64, NHD, SPL);      // stage-1 attn (36, 8, 4)
    dim3 gAT2(L / 64, NHD, 4);        // stage-2 fused LT+ST (36, 8, 4)
    dim3 gC2(L, 2);                   // combine2_both
    dim3 gDW(6, 6, 16);               // fused gn+gelu+dwconv (+stats fold)

    // ---- stage 1: self attention (5 dispatches) ----
    ln_kernel<<<L, 256, 0, stream>>>(tgt, nullptr, ln1_g, ln1_b, nullptr, t0b);
    gemm_qkv<<<gQKV, 256, 0, stream>>>(t0b, sa_Wq, sa_bq, sa_Wk, sa_bk, sa_Wv, sa_bv,
                                       qb, kb2, vtb2);
    attn_mfma_split<<<gATS, 256, 0, stream>>>(qb, kb2, vtb2, OP, ML, L, L / SPL);
    attn_combine<<<L, 256, 0, stream>>>(OP, ML, t4b);
    gemm_mfma<<<gDD, 256, 0, stream>>>(t4b, sa_Wo, sa_bo, tgt, t5, nullptr, 1.f, nullptr, L, D, D);

    // ---- stage 2: LT + ST cross-attention (6 dispatches) ----
    ln2cvt<<<L + (2 * L / 32) * (NHD + 8), 256, 0, stream>>>(
        t5, lV, ln2_g, ln2_b, ln4_g, ln4_b, t3b, t0, gK, kb1, gV, vtb1);
    gemm_mfma<<<gDD, 256, 0, stream>>>(t3b, Wq, bq, nullptr, t1, qb, S2LOG, nullptr, L, D, D);
    ln_cvtT<<<L + (L / 32) * NHD, 256, 0, stream>>>(t1, lK, ln4_g, ln4_b, kb2, t0, vtb2);
    // t0..t3 now dead -> split-K partials (LT: t0-t1, ST: t2-t3)
    attn_ltst<<<gAT2, 256, 0, stream>>>(qb, kb1, vtb1, OPlt, MLlt, kb2, vtb2, OPst, MLst);
    combine2_both<<<gC2, 256, 0, stream>>>(OPlt, MLlt, obLT, OPst, MLst, obST);
    gemm_dual<<<gDD, 256, 0, stream>>>(obLT, lt_Wo, lt_bo, obST, st_Wo, st_bo, t5, t5);

    // ---- stage 3: FFN (4 dispatches; GN stats fused into W1 epilogue) ----
    ln_kernel<<<L, 256, 0, stream>>>(t5, nullptr, ln3_g, ln3_b, nullptr, t4b);
    gemm_mfma<<<gDF, 256, 0, stream>>>(t4b, W1w, b1w, nullptr, X1, nullptr, 1.f, PS, L, FF, D);
    gn_gelu_dwconv<<<gDW, 256, 0, stream>>>(X1, PS, gn_g, gn_b, dw_k, X2b);
    gemm_mfma<<<gDD, 256, 0, stream>>>(X2b, W2w, b2w, t5, out, nullptr, 1.f, nullptr, L, D, FF);
}

// Round 18
// 307.145 us; speedup vs baseline: 1.0300x; 1.0300x over previous
//
#include <hip/hip_runtime.h>
#include <hip/hip_bf16.h>

#define L   2304
#define D   256
#define NHD 8
#define HD  32
#define FF  1024
#define HH  48
#define WWW 48
#define SPL 4     // stage-1 attention split-K factor
#define RCH 24    // gn_stats row chunks
#define RP  (L / RCH)   // 96 rows per chunk
#define S2LOG 0.25503486f   // log2(e)/sqrt(32): folded into Q bf16 copy

typedef unsigned short bfraw;
typedef __attribute__((ext_vector_type(8))) short s8v;   // 8 bf16 = 4 VGPRs
typedef __attribute__((ext_vector_type(4))) float f4v;   // MFMA C/D frag

__device__ __forceinline__ bfraw f2b(float x) {
    __hip_bfloat16 h = __float2bfloat16(x);
    return __builtin_bit_cast(bfraw, h);
}

// Diagnostic: fill output with a constant (decodable from reported absmax).
__global__ __launch_bounds__(256) void diag_kernel(float* __restrict__ out, float c, int n)
{
    int i = blockIdx.x * 256 + threadIdx.x;
    if (i < n) out[i] = c;
}

// ---------------------------------------------------------------------------
// LayerNorm over D=256. fp32 out and bf16 out both OPTIONAL (nullable).
// ---------------------------------------------------------------------------
__global__ __launch_bounds__(256) void ln_kernel(
    const float* __restrict__ inA, const float* __restrict__ inB,
    const float* __restrict__ g, const float* __restrict__ b,
    float* __restrict__ out, bfraw* __restrict__ outb)
{
    int row = blockIdx.x, t = threadIdx.x;
    size_t idx = (size_t)row * D + t;
    float v = inA[idx];
    if (inB) v += inB[idx];
    __shared__ float rs[256], rq[256];
    rs[t] = v; rq[t] = v * v;
    __syncthreads();
    for (int o = 128; o > 0; o >>= 1) {
        if (t < o) { rs[t] += rs[t + o]; rq[t] += rq[t + o]; }
        __syncthreads();
    }
    float mean = rs[0] * (1.f / D);
    float var  = rq[0] * (1.f / D) - mean * mean;
    float rstd = rsqrtf(var + 1e-5f);
    float r = (v - mean) * rstd * g[t] + b[t];
    if (out)  out[idx]  = r;
    if (outb) outb[idx] = f2b(r);
}

// ---------------------------------------------------------------------------
// Merged ln2+ln4(v_st) AND stage-2 bf16 prep (cvt of gK, cvtT of gV).
// Grid (L + (2L/32)*(NHD+8)): bx < L -> dual layernorm row; else cvt work.
// ---------------------------------------------------------------------------
__global__ __launch_bounds__(256) void ln2cvt(
    const float* __restrict__ t5, const float* __restrict__ lV,
    const float* __restrict__ g2, const float* __restrict__ b2,
    const float* __restrict__ g4, const float* __restrict__ b4,
    bfraw* __restrict__ out2b, float* __restrict__ outv,
    const float* __restrict__ gK, bfraw* __restrict__ kb1,
    const float* __restrict__ gV, bfraw* __restrict__ vtb1)
{
    __shared__ float rs[256], rq[256];
    __shared__ float Ls[32][33];
    int t = threadIdx.x;
    if (blockIdx.x < L) {
        int row = blockIdx.x;
        size_t idx = (size_t)row * D + t;
        float v = t5[idx];
        rs[t] = v; rq[t] = v * v;
        __syncthreads();
        for (int o = 128; o > 0; o >>= 1) {
            if (t < o) { rs[t] += rs[t + o]; rq[t] += rq[t + o]; }
            __syncthreads();
        }
        float mean = rs[0] * (1.f / D);
        float var  = rq[0] * (1.f / D) - mean * mean;
        float rstd = rsqrtf(var + 1e-5f);
        float r2 = (v - mean) * rstd * g2[t] + b2[t];
        out2b[idx] = f2b(r2);
        float u = r2 + lV[idx];
        __syncthreads();
        rs[t] = u; rq[t] = u * u;
        __syncthreads();
        for (int o = 128; o > 0; o >>= 1) {
            if (t < o) { rs[t] += rs[t + o]; rq[t] += rq[t + o]; }
            __syncthreads();
        }
        float mean2 = rs[0] * (1.f / D);
        float var2  = rq[0] * (1.f / D) - mean2 * mean2;
        float rstd2 = rsqrtf(var2 + 1e-5f);
        outv[idx] = (u - mean2) * rstd2 * g4[t] + b4[t];
    } else {
        int idx = blockIdx.x - L;
        int ix = idx % (2 * L / 32), iy = idx / (2 * L / 32);
        if (iy < NHD) {
            int h = iy, n0 = ix * 32;
            const int N = 2 * L;
            int nl = t >> 3, dq = t & 7;
            float4 v = *reinterpret_cast<const float4*>(gV + (size_t)(n0 + nl) * D + h * HD + dq * 4);
            Ls[nl][dq*4+0] = v.x; Ls[nl][dq*4+1] = v.y;
            Ls[nl][dq*4+2] = v.z; Ls[nl][dq*4+3] = v.w;
            __syncthreads();
            int dl = t >> 3, nq = t & 7;
            ushort4 o;
            o.x = f2b(Ls[nq*4+0][dl]); o.y = f2b(Ls[nq*4+1][dl]);
            o.z = f2b(Ls[nq*4+2][dl]); o.w = f2b(Ls[nq*4+3][dl]);
            *reinterpret_cast<ushort4*>(vtb1 + (size_t)(h * HD + dl) * N + n0 + nq * 4) = o;
        } else {
            size_t i = ((size_t)(ix * 8 + (iy - NHD)) * 256 + t) * 4;
            float4 v = *reinterpret_cast<const float4*>(gK + i);
            ushort4 o;
            o.x = f2b(v.x); o.y = f2b(v.y); o.z = f2b(v.z); o.w = f2b(v.w);
            *reinterpret_cast<ushort4*>(kb1 + i) = o;
        }
    }
}

// ---------------------------------------------------------------------------
// Merged ln(k_st) + cvtT(v_st). Grid (L + L/32*NHD = 2880).
// ---------------------------------------------------------------------------
__global__ __launch_bounds__(256) void ln_cvtT(
    const float* __restrict__ t1, const float* __restrict__ lK,
    const float* __restrict__ g4, const float* __restrict__ b4,
    bfraw* __restrict__ kb2,
    const float* __restrict__ vsrc, bfraw* __restrict__ vtb2)
{
    __shared__ float rs[256], rq[256];
    __shared__ float Ls[32][33];
    int t = threadIdx.x;
    if (blockIdx.x < L) {
        int row = blockIdx.x;
        size_t idx = (size_t)row * D + t;
        float v = t1[idx] + lK[idx];
        rs[t] = v; rq[t] = v * v;
        __syncthreads();
        for (int o = 128; o > 0; o >>= 1) {
            if (t < o) { rs[t] += rs[t + o]; rq[t] += rq[t + o]; }
            __syncthreads();
        }
        float mean = rs[0] * (1.f / D);
        float var  = rq[0] * (1.f / D) - mean * mean;
        float rstd = rsqrtf(var + 1e-5f);
        kb2[idx] = f2b((v - mean) * rstd * g4[t] + b4[t]);
    } else {
        int idx = blockIdx.x - L;
        int n0 = (idx >> 3) * 32, h = idx & 7;
        int nl = t >> 3, dq = t & 7;
        float4 v = *reinterpret_cast<const float4*>(vsrc + (size_t)(n0 + nl) * D + h * HD + dq * 4);
        Ls[nl][dq*4+0] = v.x; Ls[nl][dq*4+1] = v.y;
        Ls[nl][dq*4+2] = v.z; Ls[nl][dq*4+3] = v.w;
        __syncthreads();
        int dl = t >> 3, nq = t & 7;
        ushort4 o;
        o.x = f2b(Ls[nq*4+0][dl]); o.y = f2b(Ls[nq*4+1][dl]);
        o.z = f2b(Ls[nq*4+2][dl]); o.w = f2b(Ls[nq*4+3][dl]);
        *reinterpret_cast<ushort4*>(vtb2 + (size_t)(h * HD + dl) * L + n0 + nq * 4) = o;
    }
}

// ---------------------------------------------------------------------------
// MFMA bf16 GEMM, bf16 A input (verified R7/R13 core): C = A@W^T + bias (+res).
// A bf16 in global, fragment loaded directly (16B/lane). W fp32 staged to
// LDS 64x32 bf16, XOR swizzle. 32x64 tile, 4 waves.
// ---------------------------------------------------------------------------
__global__ __launch_bounds__(256) void gemm_mfma(
    const bfraw* __restrict__ A, const float* __restrict__ W,
    const float* __restrict__ bias, const float* res, float* out,
    bfraw* __restrict__ outb, float oscale,
    int M, int N, int K)
{
    __shared__ __attribute__((aligned(16))) short Wl[64][32];
    int t = threadIdx.x;
    int w = t >> 6, l = t & 63;
    int lo = l & 15, quad = l >> 4;
    int m0 = blockIdx.x * 32, n0 = blockIdx.y * 64;
    int wr = (w & 1) * 16, wc = (w >> 1) * 32;
    f4v acc[2];
    acc[0] = (f4v){0.f, 0.f, 0.f, 0.f};
    acc[1] = (f4v){0.f, 0.f, 0.f, 0.f};

    int aswz = (quad ^ ((lo >> 2) & 3)) * 8;   // swizzled k-group for W reads
    int srow = t >> 3, spart = t & 7;          // W staging: 32 rows x 8 quads
    const bfraw* ap = A + (size_t)(m0 + wr + lo) * K + quad * 8;

    for (int k0 = 0; k0 < K; k0 += 32) {
        float4 w4[2];
        #pragma unroll
        for (int i = 0; i < 2; i++)
            w4[i] = *reinterpret_cast<const float4*>(W + (size_t)(n0 + i * 32 + srow) * K + k0 + spart * 4);
        s8v af = *reinterpret_cast<const s8v*>(ap + k0);
        __syncthreads();
        #pragma unroll
        for (int i = 0; i < 2; i++) {
            int row = i * 32 + srow;
            int col = ((spart >> 1) ^ ((row >> 2) & 3)) * 8 + (spart & 1) * 4;
            ushort4 wb;
            wb.x = f2b(w4[i].x); wb.y = f2b(w4[i].y); wb.z = f2b(w4[i].z); wb.w = f2b(w4[i].w);
            *reinterpret_cast<ushort4*>(&Wl[row][col]) = wb;
        }
        __syncthreads();
        #pragma unroll
        for (int j = 0; j < 2; j++) {
            int rw = wc + j * 16 + lo;
            s8v wf = *reinterpret_cast<const s8v*>(&Wl[rw][aswz]);
            acc[j] = __builtin_amdgcn_mfma_f32_16x16x32_bf16(af, wf, acc[j], 0, 0, 0);
        }
    }

    #pragma unroll
    for (int j = 0; j < 2; j++) {
        #pragma unroll
        for (int r = 0; r < 4; r++) {
            int mrow = m0 + wr + quad * 4 + r;
            int ncol = n0 + wc + j * 16 + lo;
            float v = acc[j][r] + bias[ncol];
            size_t idx = (size_t)mrow * N + ncol;
            if (res) v += res[idx];
            if (out) out[idx] = v;
            if (outb) outb[idx] = f2b(v * oscale);
        }
    }
}

// ---------------------------------------------------------------------------
// DUAL GEMM: out = res + A1@W1^T + b1 + A2@W2^T + b2 (M=L, N=K=D fixed).
// ---------------------------------------------------------------------------
__global__ __launch_bounds__(256) void gemm_dual(
    const bfraw* __restrict__ A1, const float* __restrict__ W1, const float* __restrict__ b1,
    const bfraw* __restrict__ A2, const float* __restrict__ W2, const float* __restrict__ b2,
    const float* __restrict__ res, float* __restrict__ out)
{
    __shared__ __attribute__((aligned(16))) short Wl[64][32];
    int t = threadIdx.x;
    int w = t >> 6, l = t & 63;
    int lo = l & 15, quad = l >> 4;
    int m0 = blockIdx.x * 32, n0 = blockIdx.y * 64;
    int wr = (w & 1) * 16, wc = (w >> 1) * 32;
    f4v acc[2];
    acc[0] = (f4v){0.f, 0.f, 0.f, 0.f};
    acc[1] = (f4v){0.f, 0.f, 0.f, 0.f};

    int aswz = (quad ^ ((lo >> 2) & 3)) * 8;
    int srow = t >> 3, spart = t & 7;

    #pragma unroll
    for (int half = 0; half < 2; half++) {
        const bfraw* ap = (half ? A2 : A1) + (size_t)(m0 + wr + lo) * D + quad * 8;
        const float* W  = half ? W2 : W1;
        for (int k0 = 0; k0 < D; k0 += 32) {
            float4 w4[2];
            #pragma unroll
            for (int i = 0; i < 2; i++)
                w4[i] = *reinterpret_cast<const float4*>(W + (size_t)(n0 + i * 32 + srow) * D + k0 + spart * 4);
            s8v af = *reinterpret_cast<const s8v*>(ap + k0);
            __syncthreads();
            #pragma unroll
            for (int i = 0; i < 2; i++) {
                int row = i * 32 + srow;
                int col = ((spart >> 1) ^ ((row >> 2) & 3)) * 8 + (spart & 1) * 4;
                ushort4 wb;
                wb.x = f2b(w4[i].x); wb.y = f2b(w4[i].y); wb.z = f2b(w4[i].z); wb.w = f2b(w4[i].w);
                *reinterpret_cast<ushort4*>(&Wl[row][col]) = wb;
            }
            __syncthreads();
            #pragma unroll
            for (int j = 0; j < 2; j++) {
                int rw = wc + j * 16 + lo;
                s8v wf = *reinterpret_cast<const s8v*>(&Wl[rw][aswz]);
                acc[j] = __builtin_amdgcn_mfma_f32_16x16x32_bf16(af, wf, acc[j], 0, 0, 0);
            }
        }
    }

    #pragma unroll
    for (int j = 0; j < 2; j++) {
        #pragma unroll
        for (int r = 0; r < 4; r++) {
            int mrow = m0 + wr + quad * 4 + r;
            int ncol = n0 + wc + j * 16 + lo;
            size_t idx = (size_t)mrow * D + ncol;
            out[idx] = acc[j][r] + b1[ncol] + b2[ncol] + res[idx];
        }
    }
}

// ---------------------------------------------------------------------------
// Fused QKV projection (stage 1). Grid (L/32, 12): sel = by>>2 picks Q/K/V,
// n0 = (by&3)*64. Q -> qb bf16 (S2LOG); K -> kb bf16; V -> vtb TRANSPOSED.
// ---------------------------------------------------------------------------
__global__ __launch_bounds__(256) void gemm_qkv(
    const bfraw* __restrict__ A,
    const float* __restrict__ Wq_, const float* __restrict__ bq_,
    const float* __restrict__ Wk_, const float* __restrict__ bk_,
    const float* __restrict__ Wv_, const float* __restrict__ bv_,
    bfraw* __restrict__ qb, bfraw* __restrict__ kb, bfraw* __restrict__ vtb)
{
    __shared__ __attribute__((aligned(16))) short Wl[64][32];
    int t = threadIdx.x;
    int w = t >> 6, l = t & 63;
    int lo = l & 15, quad = l >> 4;
    int sel = blockIdx.y >> 2;
    int m0 = blockIdx.x * 32, n0 = (blockIdx.y & 3) * 64;
    int wr = (w & 1) * 16, wc = (w >> 1) * 32;
    const float* W    = (sel == 0) ? Wq_ : (sel == 1) ? Wk_ : Wv_;
    const float* bias = (sel == 0) ? bq_ : (sel == 1) ? bk_ : bv_;
    f4v acc[2];
    acc[0] = (f4v){0.f, 0.f, 0.f, 0.f};
    acc[1] = (f4v){0.f, 0.f, 0.f, 0.f};

    int aswz = (quad ^ ((lo >> 2) & 3)) * 8;
    int srow = t >> 3, spart = t & 7;
    const bfraw* ap = A + (size_t)(m0 + wr + lo) * D + quad * 8;

    for (int k0 = 0; k0 < D; k0 += 32) {
        float4 w4[2];
        #pragma unroll
        for (int i = 0; i < 2; i++)
            w4[i] = *reinterpret_cast<const float4*>(W + (size_t)(n0 + i * 32 + srow) * D + k0 + spart * 4);
        s8v af = *reinterpret_cast<const s8v*>(ap + k0);
        __syncthreads();
        #pragma unroll
        for (int i = 0; i < 2; i++) {
            int row = i * 32 + srow;
            int col = ((spart >> 1) ^ ((row >> 2) & 3)) * 8 + (spart & 1) * 4;
            ushort4 wb;
            wb.x = f2b(w4[i].x); wb.y = f2b(w4[i].y); wb.z = f2b(w4[i].z); wb.w = f2b(w4[i].w);
            *reinterpret_cast<ushort4*>(&Wl[row][col]) = wb;
        }
        __syncthreads();
        #pragma unroll
        for (int j = 0; j < 2; j++) {
            int rw = wc + j * 16 + lo;
            s8v wf = *reinterpret_cast<const s8v*>(&Wl[rw][aswz]);
            acc[j] = __builtin_amdgcn_mfma_f32_16x16x32_bf16(af, wf, acc[j], 0, 0, 0);
        }
    }

    #pragma unroll
    for (int j = 0; j < 2; j++) {
        #pragma unroll
        for (int r = 0; r < 4; r++) {
            int mrow = m0 + wr + quad * 4 + r;
            int ncol = n0 + wc + j * 16 + lo;
            float v = acc[j][r] + bias[ncol];
            if (sel == 0)      qb[(size_t)mrow * D + ncol] = f2b(v * S2LOG);
            else if (sel == 1) kb[(size_t)mrow * D + ncol] = f2b(v);
            else               vtb[(size_t)ncol * L + mrow] = f2b(v);   // transposed
        }
    }
}

// ---------------------------------------------------------------------------
// Attention core, FIXED-SHIFT softmax, DOUBLE-BUFFERED K/V staging (R16-
// verified): one barrier per 64-key step. PV swapped (mfma(V,P));
// LDS-transpose epilogue. OP unnormalized; ML stores just l per query.
// ---------------------------------------------------------------------------
__device__ __forceinline__ void attn_core(
    const bfraw* __restrict__ Qb, const bfraw* __restrict__ Kb,
    const bfraw* __restrict__ Vt, float* __restrict__ OP,
    float* __restrict__ ML, int Lk, int chunk, int zz,
    short (*Ks)[64][32], short (*Vts)[32][72], short (*Ps)[72], float (*Tb)[33])
{
    int t = threadIdx.x;
    int w = t >> 6, l = t & 63;
    int h = blockIdx.y, q0 = blockIdx.x * 64 + w * 16;
    int lo = l & 15, quad = l >> 4;
    int kb = zz * chunk, ke = kb + chunk;

    s8v qf = *reinterpret_cast<const s8v*>(Qb + (size_t)(q0 + lo) * D + h * HD + quad * 8);
    int kswz = (quad ^ ((lo >> 2) & 3)) * 8;

    int skey = t >> 2, spart = t & 3;
    int kcol = (spart ^ ((skey >> 2) & 3)) * 8;
    int sd = t >> 3, svp = t & 7;
    const bfraw* kp = Kb + (size_t)skey * D + h * HD + spart * 8;
    const bfraw* vp = Vt + (size_t)(h * HD + sd) * Lk + svp * 8;

    // prologue: stage first tile into buf 0
    {
        s8v kv = *reinterpret_cast<const s8v*>(kp + (size_t)kb * D);
        s8v vv = *reinterpret_cast<const s8v*>(vp + kb);
        *reinterpret_cast<s8v*>(&Ks[0][skey][kcol]) = kv;
        *reinterpret_cast<s8v*>(&Vts[0][sd][svp * 8]) = vv;
    }
    __syncthreads();

    float l_r = 0.f;
    f4v o0 = {0.f, 0.f, 0.f, 0.f}, o1 = {0.f, 0.f, 0.f, 0.f};
    int cur = 0;

    for (int k0 = kb; k0 < ke; k0 += 64) {
        bool hasNext = (k0 + 64) < ke;
        s8v nkv, nvv;
        if (hasNext) {
            nkv = *reinterpret_cast<const s8v*>(kp + (size_t)(k0 + 64) * D);
            nvv = *reinterpret_cast<const s8v*>(vp + (k0 + 64));
        }

        f4v sc4[4];
        #pragma unroll
        for (int s = 0; s < 4; s++) {
            s8v kf = *reinterpret_cast<const s8v*>(&Ks[cur][lo + 16 * s][kswz]);
            sc4[s] = __builtin_amdgcn_mfma_f32_16x16x32_bf16(kf, qf, (f4v){0.f,0.f,0.f,0.f}, 0, 0, 0);
        }
        float ls = 0.f;
        #pragma unroll
        for (int s = 0; s < 4; s++) {
            float p0 = __builtin_amdgcn_exp2f(sc4[s][0]);
            float p1 = __builtin_amdgcn_exp2f(sc4[s][1]);
            float p2 = __builtin_amdgcn_exp2f(sc4[s][2]);
            float p3 = __builtin_amdgcn_exp2f(sc4[s][3]);
            ls += p0 + p1 + p2 + p3;
            ushort4 pk;
            pk.x = f2b(p0); pk.y = f2b(p1); pk.z = f2b(p2); pk.w = f2b(p3);
            *reinterpret_cast<ushort4*>(&Ps[lo][s * 16 + quad * 4]) = pk;
        }
        ls += __shfl_xor(ls, 16);
        ls += __shfl_xor(ls, 32);
        l_r += ls;
        #pragma unroll
        for (int kc = 0; kc < 2; kc++) {
            s8v pf = *reinterpret_cast<const s8v*>(&Ps[lo][kc * 32 + quad * 8]);
            s8v v0 = *reinterpret_cast<const s8v*>(&Vts[cur][lo][kc * 32 + quad * 8]);
            s8v v1 = *reinterpret_cast<const s8v*>(&Vts[cur][16 + lo][kc * 32 + quad * 8]);
            o0 = __builtin_amdgcn_mfma_f32_16x16x32_bf16(v0, pf, o0, 0, 0, 0);
            o1 = __builtin_amdgcn_mfma_f32_16x16x32_bf16(v1, pf, o1, 0, 0, 0);
        }

        if (hasNext) {
            *reinterpret_cast<s8v*>(&Ks[cur ^ 1][skey][kcol]) = nkv;
            *reinterpret_cast<s8v*>(&Vts[cur ^ 1][sd][svp * 8]) = nvv;
        }
        __syncthreads();   // buf^1 writes visible AND buf reads done
        cur ^= 1;
    }

    #pragma unroll
    for (int r = 0; r < 4; r++) {
        Tb[lo][quad * 4 + r]      = o0[r];
        Tb[lo][16 + quad * 4 + r] = o1[r];
    }
    float* Oz = OP + (size_t)zz * L * D;
    int ql = l >> 2, dq = (l & 3) * 8;
    float4 u0, u1;
    u0.x = Tb[ql][dq + 0]; u0.y = Tb[ql][dq + 1];
    u0.z = Tb[ql][dq + 2]; u0.w = Tb[ql][dq + 3];
    u1.x = Tb[ql][dq + 4]; u1.y = Tb[ql][dq + 5];
    u1.z = Tb[ql][dq + 6]; u1.w = Tb[ql][dq + 7];
    *reinterpret_cast<float4*>(Oz + (size_t)(q0 + ql) * D + h * HD + dq)     = u0;
    *reinterpret_cast<float4*>(Oz + (size_t)(q0 + ql) * D + h * HD + dq + 4) = u1;
    if (l < 16)
        ML[((size_t)zz * NHD + h) * L + q0 + lo] = l_r;
}

// Stage-1 self attention, SPL=4. Grid (L/64, NHD, SPL).
__global__ __launch_bounds__(256) void attn_mfma_split(
    const bfraw* __restrict__ Qb, const bfraw* __restrict__ Kb,
    const bfraw* __restrict__ Vt, float* __restrict__ OP,
    float* __restrict__ ML, int Lk, int chunk)
{
    __shared__ __attribute__((aligned(16))) short Ks[2][64][32];
    __shared__ __attribute__((aligned(16))) short Vts[2][32][72];
    __shared__ __attribute__((aligned(16))) short Ps[4][16][72];
    __shared__ float Tb[4][16][33];
    int w = threadIdx.x >> 6;
    attn_core(Qb, Kb, Vt, OP, ML, Lk, chunk, blockIdx.z, Ks, Vts, Ps[w], Tb[w]);
}

// Stage-2 fused LT+ST attention, SPL=2 each. Grid (L/64, NHD, 4):
// z<2 -> LT chunk z; z>=2 -> ST chunk z-2.
__global__ __launch_bounds__(256) void attn_ltst(
    const bfraw* __restrict__ Qb,
    const bfraw* __restrict__ K_lt, const bfraw* __restrict__ V_lt,
    float* __restrict__ OP_lt, float* __restrict__ ML_lt,
    const bfraw* __restrict__ K_st, const bfraw* __restrict__ V_st,
    float* __restrict__ OP_st, float* __restrict__ ML_st)
{
    __shared__ __attribute__((aligned(16))) short Ks[2][64][32];
    __shared__ __attribute__((aligned(16))) short Vts[2][32][72];
    __shared__ __attribute__((aligned(16))) short Ps[4][16][72];
    __shared__ float Tb[4][16][33];
    int w = threadIdx.x >> 6;
    int z = blockIdx.z;
    if (z < 2)
        attn_core(Qb, K_lt, V_lt, OP_lt, ML_lt, 2 * L, L, z, Ks, Vts, Ps[w], Tb[w]);
    else
        attn_core(Qb, K_st, V_st, OP_st, ML_st, L, L / 2, z - 2, Ks, Vts, Ps[w], Tb[w]);
}

// Stage-1 combine, SPL=4: equal-weight (fixed-shift softmax) -> bf16.
__global__ __launch_bounds__(256) void attn_combine(
    const float* __restrict__ OP, const float* __restrict__ ML,
    bfraw* __restrict__ Ob)
{
    int q = blockIdx.x, t = threadIdx.x, h = t >> 5;
    float wl = 0.f, acc = 0.f;
    #pragma unroll
    for (int s = 0; s < SPL; s++) {
        wl  += ML[((size_t)s * NHD + h) * L + q];
        acc += OP[(size_t)s * L * D + (size_t)q * D + t];
    }
    Ob[(size_t)q * D + t] = f2b(acc / wl);
}

// Stage-2 combine for BOTH lt and st, SPL=2. Grid (L, 2).
__global__ __launch_bounds__(256) void combine2_both(
    const float* __restrict__ OP_lt, const float* __restrict__ ML_lt, bfraw* __restrict__ Ob_lt,
    const float* __restrict__ OP_st, const float* __restrict__ ML_st, bfraw* __restrict__ Ob_st)
{
    int q = blockIdx.x, t = threadIdx.x, h = t >> 5;
    const float* OP = blockIdx.y ? OP_st : OP_lt;
    const float* ML = blockIdx.y ? ML_st : ML_lt;
    bfraw* Ob = blockIdx.y ? Ob_st : Ob_lt;
    float wl = 0.f, acc = 0.f;
    #pragma unroll
    for (int s = 0; s < 2; s++) {
        wl  += ML[((size_t)s * NHD + h) * L + q];
        acc += OP[(size_t)s * L * D + (size_t)q * D + t];
    }
    Ob[(size_t)q * D + t] = f2b(acc / wl);
}

// ---------------------------------------------------------------------------
// GroupNorm stats, stage A: grid (32, RCH) -> partial (sum, sumsq).
// ---------------------------------------------------------------------------
__global__ __launch_bounds__(256) void gn_stats_part(
    const float* __restrict__ X, float* __restrict__ ps)
{
    int g = blockIdx.x, rc = blockIdx.y, t = threadIdx.x;
    int cq = (t & 7) * 4;
    int rl = t >> 3;
    int r0 = rc * RP;
    float s = 0.f, sq = 0.f;
    #pragma unroll
    for (int p = 0; p < RP / 32; p++) {
        int l = r0 + p * 32 + rl;
        float4 v = *reinterpret_cast<const float4*>(X + (size_t)l * FF + g * 32 + cq);
        s  += v.x + v.y + v.z + v.w;
        sq += v.x*v.x + v.y*v.y + v.z*v.z + v.w*v.w;
    }
    __shared__ float rs[256], rq[256];
    rs[t] = s; rq[t] = sq;
    __syncthreads();
    for (int o = 128; o > 0; o >>= 1) {
        if (t < o) { rs[t] += rs[t + o]; rq[t] += rq[t + o]; }
        __syncthreads();
    }
    if (t == 0) {
        ps[(g * RCH + rc) * 2]     = rs[0];
        ps[(g * RCH + rc) * 2 + 1] = rq[0];
    }
}

// ---------------------------------------------------------------------------
// Fused GN + exact-GELU + depthwise 5x5 conv with INLINE stats fold
// (each thread folds its group's RCH partials -- L2-broadcast reads).
// Grid (6,6,16); 12x12 halo in LDS; output bf16 (feeds W2 GEMM).
// ---------------------------------------------------------------------------
__global__ __launch_bounds__(256) void gn_gelu_dwconv(
    const float* __restrict__ X, const float* __restrict__ ps,
    const float* __restrict__ gg, const float* __restrict__ gb,
    const float* __restrict__ Kw, bfraw* __restrict__ Y)
{
    __shared__ float tile[144][64];
    int h0 = blockIdx.x * 8, w0 = blockIdx.y * 8, c0 = blockIdx.z * 64;
    int t = threadIdx.x;
    int c = t & 63;
    int cg = (c0 + c) >> 5;
    float s = 0.f, sq = 0.f;
    #pragma unroll
    for (int i = 0; i < RCH; i++) {
        s  += ps[(cg * RCH + i) * 2];
        sq += ps[(cg * RCH + i) * 2 + 1];
    }
    float n = (float)(L * 32);
    float mu = s / n;
    float rs = rsqrtf(sq / n - mu * mu + 1e-5f);
    float ga = gg[c0 + c], be = gb[c0 + c];

    for (int i = t; i < 144 * 64; i += 256) {
        int sp = i >> 6;
        int hy = h0 + (sp / 12) - 2, wx = w0 + (sp % 12) - 2;
        float v = 0.f;
        if (hy >= 0 && hy < HH && wx >= 0 && wx < WWW) {
            float x = X[(size_t)(hy * WWW + wx) * FF + c0 + c];
            x = (x - mu) * rs * ga + be;
            v = 0.5f * x * (1.f + erff(x * 0.70710678118654752f));
        }
        tile[sp][c] = v;
    }
    float kw[25];
    #pragma unroll
    for (int i = 0; i < 25; i++) kw[i] = Kw[(size_t)(c0 + c) * 25 + i];
    __syncthreads();

    int sgrp = t >> 6;
    for (int sIdx = 0; sIdx < 16; sIdx++) {
        int sp = sgrp * 16 + sIdx;
        int oh = sp >> 3, ow = sp & 7;
        float acc = 0.f;
        #pragma unroll
        for (int ky = 0; ky < 5; ky++)
            #pragma unroll
            for (int kx = 0; kx < 5; kx++)
                acc += tile[(oh + ky) * 12 + ow + kx][c] * kw[ky * 5 + kx];
        Y[(size_t)((h0 + oh) * WWW + w0 + ow) * FF + c0 + c] = f2b(acc);
    }
}

// ---------------------------------------------------------------------------
extern "C" void kernel_launch(void* const* d_in, const int* in_sizes, int n_in,
                              void* d_out, int out_size, void* d_ws, size_t ws_size,
                              hipStream_t stream)
{
    (void)in_sizes;
    float* out = (float*)d_out;   // reference output dtype is float32

    if (n_in != 34) {
        diag_kernel<<<(out_size + 255) / 256, 256, 0, stream>>>(out, 2000.f, out_size);
        return;
    }

    const float* tgt    = (const float*)d_in[0];
    const float* gK     = (const float*)d_in[1];
    const float* gV     = (const float*)d_in[2];
    const float* lK     = (const float*)d_in[3];
    const float* lV     = (const float*)d_in[4];
    const float* ln1_g  = (const float*)d_in[5];
    const float* ln1_b  = (const float*)d_in[6];
    const float* ln2_g  = (const float*)d_in[7];
    const float* ln2_b  = (const float*)d_in[8];
    const float* ln3_g  = (const float*)d_in[9];
    const float* ln3_b  = (const float*)d_in[10];
    const float* ln4_g  = (const float*)d_in[11];
    const float* ln4_b  = (const float*)d_in[12];
    const float* sa_Wq  = (const float*)d_in[13];
    const float* sa_bq  = (const float*)d_in[14];
    const float* sa_Wk  = (const float*)d_in[15];
    const float* sa_bk  = (const float*)d_in[16];
    const float* sa_Wv  = (const float*)d_in[17];
    const float* sa_bv  = (const float*)d_in[18];
    const float* sa_Wo  = (const float*)d_in[19];
    const float* sa_bo  = (const float*)d_in[20];
    const float* Wq     = (const float*)d_in[21];
    const float* bq     = (const float*)d_in[22];
    const float* lt_Wo  = (const float*)d_in[23];
    const float* lt_bo  = (const float*)d_in[24];
    const float* st_Wo  = (const float*)d_in[25];
    const float* st_bo  = (const float*)d_in[26];
    const float* W1w    = (const float*)d_in[27];
    const float* b1w    = (const float*)d_in[28];
    const float* gn_g   = (const float*)d_in[29];
    const float* gn_b   = (const float*)d_in[30];
    const float* dw_k   = (const float*)d_in[31];
    const float* W2w    = (const float*)d_in[32];
    const float* b2w    = (const float*)d_in[33];

    // Workspace layout (see R7/R10/R13).
    const size_t LD = (size_t)L * D;
    const size_t NEED = (6 * LD + (size_t)L * FF + 64) * 4;
    float* ws = (float*)d_ws;
    float* t0 = ws + 0 * LD;
    float* t1 = ws + 1 * LD;
    float* t2 = ws + 2 * LD;
    float* t3 = ws + 3 * LD;
    float* t4 = ws + 4 * LD;
    float* t5 = ws + 5 * LD;
    float* X1 = t0;                   // [L,FF], spans t0..t3 (dead in stage 3)
    float* X2 = ws + 6 * LD;          // [L,FF] region
    bfraw* qb   = (bfraw*)X2;
    bfraw* kb1  = qb + LD;            // gK bf16 (2L)
    bfraw* vtb1 = qb + 3 * LD;        // gV^T bf16 (2L)
    bfraw* kb2  = qb + 5 * LD;        // self/st K bf16 (L)
    bfraw* vtb2 = qb + 6 * LD;        // self/st V^T bf16 (L)
    float* OP   = ws;                 // stage-1 partials: [4][L][D] = t0..t3
    float* OPlt = t0;                 // stage-2 LT partials: [2][L][D]
    float* OPst = t2;                 // stage-2 ST partials: [2][L][D]
    float* ML   = X2 + (7 * LD) / 2;  // stage-1 ML [4][NHD][L] (X2 slack)
    float* MLlt = ML;                 // stage-2 LT ML [2][NHD][L]
    float* MLst = ML + 2 * (size_t)NHD * L;
    float* PS   = ML;                 // gn_stats partials [32][RCH][2] (stage 3)
    bfraw* t0b  = (bfraw*)t0;
    bfraw* t3b  = (bfraw*)t3;
    bfraw* t4b  = (bfraw*)t4;
    bfraw* obLT = t4b;
    bfraw* obST = t4b + LD;
    bfraw* X2b  = (bfraw*)X2;         // conv out bf16 (attn bufs dead in stage 3)

    if (ws_size < NEED) {
        int wsMiB = (int)(ws_size >> 20); if (wsMiB > 63) wsMiB = 63;
        diag_kernel<<<(out_size + 255) / 256, 256, 0, stream>>>(out, 64.f + (float)wsMiB, out_size);
        return;
    }

    dim3 gDD(L / 32, D / 64);         // (72, 4)
    dim3 gDF(L / 32, FF / 64);        // (72, 16)
    dim3 gQKV(L / 32, 12);            // fused QKV
    dim3 gATS(L / 64, NHD, SPL);      // stage-1 attn (36, 8, 4)
    dim3 gAT2(L / 64, NHD, 4);        // stage-2 fused LT+ST (36, 8, 4)
    dim3 gC2(L, 2);                   // combine2_both
    dim3 gGN(32, RCH);                // gn_stats stage A
    dim3 gDW(6, 6, 16);               // fused gn+gelu+dwconv

    // ---- stage 1: self attention (5 dispatches) ----
    ln_kernel<<<L, 256, 0, stream>>>(tgt, nullptr, ln1_g, ln1_b, nullptr, t0b);
    gemm_qkv<<<gQKV, 256, 0, stream>>>(t0b, sa_Wq, sa_bq, sa_Wk, sa_bk, sa_Wv, sa_bv,
                                       qb, kb2, vtb2);
    attn_mfma_split<<<gATS, 256, 0, stream>>>(qb, kb2, vtb2, OP, ML, L, L / SPL);
    attn_combine<<<L, 256, 0, stream>>>(OP, ML, t4b);
    gemm_mfma<<<gDD, 256, 0, stream>>>(t4b, sa_Wo, sa_bo, tgt, t5, nullptr, 1.f, L, D, D);

    // ---- stage 2: LT + ST cross-attention (6 dispatches) ----
    ln2cvt<<<L + (2 * L / 32) * (NHD + 8), 256, 0, stream>>>(
        t5, lV, ln2_g, ln2_b, ln4_g, ln4_b, t3b, t0, gK, kb1, gV, vtb1);
    gemm_mfma<<<gDD, 256, 0, stream>>>(t3b, Wq, bq, nullptr, t1, qb, S2LOG, L, D, D);
    ln_cvtT<<<L + (L / 32) * NHD, 256, 0, stream>>>(t1, lK, ln4_g, ln4_b, kb2, t0, vtb2);
    // t0..t3 now dead -> split-K partials (LT: t0-t1, ST: t2-t3)
    attn_ltst<<<gAT2, 256, 0, stream>>>(qb, kb1, vtb1, OPlt, MLlt, kb2, vtb2, OPst, MLst);
    combine2_both<<<gC2, 256, 0, stream>>>(OPlt, MLlt, obLT, OPst, MLst, obST);
    gemm_dual<<<gDD, 256, 0, stream>>>(obLT, lt_Wo, lt_bo, obST, st_Wo, st_bo, t5, t5);

    // ---- stage 3: FFN (5 dispatches) ----
    ln_kernel<<<L, 256, 0, stream>>>(t5, nullptr, ln3_g, ln3_b, nullptr, t4b);
    gemm_mfma<<<gDF, 256, 0, stream>>>(t4b, W1w, b1w, nullptr, X1, nullptr, 1.f, L, FF, D);
    gn_stats_part<<<gGN, 256, 0, stream>>>(X1, PS);
    gn_gelu_dwconv<<<gDW, 256, 0, stream>>>(X1, PS, gn_g, gn_b, dw_k, X2b);
    gemm_mfma<<<gDD, 256, 0, stream>>>(X2b, W2w, b2w, t5, out, nullptr, 1.f, L, D, FF);
}